// Round 1
// baseline (500.715 us; speedup 1.0000x reference)
//
#include <hip/hip_runtime.h>

typedef _Float16 f16;
typedef _Float16 f16x4 __attribute__((ext_vector_type(4)));
typedef _Float16 f16x8 __attribute__((ext_vector_type(8)));
typedef float f32x4 __attribute__((ext_vector_type(4)));

#define DM 2048
#define NT 4096
#define SEQ 2048
#define HD 128
#define NBH 32
#define SCALE 0.08838834764831845f

__device__ __forceinline__ void gload16(const f16* g, f16* l) {
  __builtin_amdgcn_global_load_lds(
      (const __attribute__((address_space(1))) void*)g,
      (__attribute__((address_space(3))) void*)l, 16, 0, 0);
}

__global__ __launch_bounds__(256) void cvt_f32_f16(const float* __restrict__ src,
                                                   f16* __restrict__ dst, int n4) {
  int i = blockIdx.x * 256 + threadIdx.x;
  int st = gridDim.x * 256;
  for (; i < n4; i += st) {
    float4 v = ((const float4*)src)[i];
    f16x4 h = {(f16)v.x, (f16)v.y, (f16)v.z, (f16)v.w};
    ((f16x4*)dst)[i] = h;
  }
}

// C = A(4096xK) * B^T, B row-major [N][K]=[2048][2048]. 128x128 tile, BK=32.
// MODE 0: f32 out [n][2048] + bias (final O projection)
// MODE 1: f16 out in [b,h,s,d] head layout, (optional bias), * scale   (Q, K)
// MODE 2: f16 out in [b,h,d,s] transposed head layout + bias           (V)
template <int MODE>
__global__ __launch_bounds__(256, 2) void gemm_bt(const f16* __restrict__ A,
                                                  const f16* __restrict__ B,
                                                  const float* __restrict__ bias,
                                                  float* __restrict__ outF,
                                                  f16* __restrict__ outH, float scale) {
  __shared__ __align__(16) f16 lA[128 * 32];
  __shared__ __align__(16) f16 lB[128 * 32];
  const int tid = threadIdx.x;
  const int w = tid >> 6, l = tid & 63;
  const int wr = w >> 1, wc = w & 1;
  const int row0 = blockIdx.y * 128, col0 = blockIdx.x * 128;

  f32x4 acc[4][4] = {};

  const int srow = w * 32 + (l >> 2);  // staging row (c=0); +16 for c=1
  const int sk = (l & 3) * 8;
  const f16* gA = A + (size_t)(row0 + srow) * DM + sk;
  const f16* gB = B + (size_t)(col0 + srow) * DM + sk;
  f16* sA = lA + w * 1024;
  f16* sB = lB + w * 1024;

  for (int k0 = 0; k0 < DM; k0 += 32) {
    __syncthreads();
    gload16(gA + k0, sA);
    gload16(gA + k0 + 16 * DM, sA + 512);
    gload16(gB + k0, sB);
    gload16(gB + k0 + 16 * DM, sB + 512);
    __syncthreads();
    f16x8 af[4], bf[4];
#pragma unroll
    for (int i = 0; i < 4; i++)
      af[i] = *(const f16x8*)&lA[(wr * 64 + i * 16 + (l & 15)) * 32 + (l >> 4) * 8];
#pragma unroll
    for (int i = 0; i < 4; i++)
      bf[i] = *(const f16x8*)&lB[(wc * 64 + i * 16 + (l & 15)) * 32 + (l >> 4) * 8];
#pragma unroll
    for (int mi = 0; mi < 4; mi++)
#pragma unroll
      for (int ni = 0; ni < 4; ni++)
        acc[mi][ni] = __builtin_amdgcn_mfma_f32_16x16x32_f16(af[mi], bf[ni], acc[mi][ni], 0, 0, 0);
  }

  const int r0 = row0 + wr * 64 + (l >> 4) * 4;
  const int c0 = col0 + wc * 64 + (l & 15);
#pragma unroll
  for (int mi = 0; mi < 4; mi++) {
#pragma unroll
    for (int ni = 0; ni < 4; ni++) {
      const int col = c0 + ni * 16;
      const float bi = bias ? bias[col] : 0.0f;
#pragma unroll
      for (int j = 0; j < 4; j++) {
        const int row = r0 + mi * 16 + j;
        const float v = acc[mi][ni][j] + bi;
        if constexpr (MODE == 0) {
          outF[(size_t)row * DM + col] = v;
        } else if constexpr (MODE == 1) {
          const int b = row >> 11, s = row & 2047, h = col >> 7, d = col & 127;
          outH[((size_t)(b * 16 + h) * SEQ + s) * HD + d] = (f16)(v * scale);
        } else {
          const int b = row >> 11, s = row & 2047, h = col >> 7, d = col & 127;
          outH[((size_t)(b * 16 + h) * HD + d) * SEQ + s] = (f16)v;
        }
      }
    }
  }
}

// Attention: one block = 64 q rows of one (b,h). Two passes over K/V in 64-key blocks.
// Q/K in [bh][s][d] f16, V transposed [bh][d][s] f16.
// Writes normalized P (f32) to Pout and O (f16, [n][2048] merged-head layout) to Oout.
__global__ __launch_bounds__(256, 2) void attn(const f16* __restrict__ Q,
                                               const f16* __restrict__ Kt,
                                               const f16* __restrict__ Vt,
                                               float* __restrict__ Pout,
                                               f16* __restrict__ Oout) {
  __shared__ __align__(16) f16 lQ[64 * 128];
  __shared__ __align__(16) f16 lK[64 * 128];
  __shared__ __align__(16) f16 lV[128 * 64];
  __shared__ __align__(16) f16 lP[64 * 64];
  const int tid = threadIdx.x, w = tid >> 6, l = tid & 63;
  const int bh = blockIdx.y, q0 = blockIdx.x * 64;
  const f16* Qb = Q + (size_t)bh * SEQ * HD;
  const f16* Kb = Kt + (size_t)bh * SEQ * HD;
  const f16* Vb = Vt + (size_t)bh * HD * SEQ;

  // stage Q, swizzled: LDS linear dest, inverse-swizzled global source
  {
    const int t = l >> 4, sl = l & 15;
#pragma unroll
    for (int c = 0; c < 4; c++) {
      const int row = w * 16 + c * 4 + t;
      const int ch = sl ^ (row & 7);
      gload16(Qb + (size_t)(q0 + row) * HD + ch * 8, lQ + w * 2048 + c * 512);
    }
  }
  __syncthreads();
  f16x8 qf[4];
  {
    const int row = w * 16 + (l & 15);
#pragma unroll
    for (int g = 0; g < 4; g++) {
      const int ch = (g * 4 + (l >> 4)) ^ (row & 7);
      qf[g] = *(const f16x8*)&lQ[row * 128 + ch * 8];
    }
  }

  float lsum[4] = {0.f, 0.f, 0.f, 0.f};
  // ---- pass 1: row sums of exp(S) (no max shift needed; scores are O(1), fp32 exp safe)
  for (int kb = 0; kb < 32; ++kb) {
    __syncthreads();
    {
      const int t = l >> 4, sl = l & 15;
#pragma unroll
      for (int c = 0; c < 4; c++) {
        const int row = w * 16 + c * 4 + t;
        const int ch = sl ^ (row & 7);
        gload16(Kb + (size_t)(kb * 64 + row) * HD + ch * 8, lK + w * 2048 + c * 512);
      }
    }
    __syncthreads();
#pragma unroll
    for (int cb = 0; cb < 4; ++cb) {
      f32x4 s = {0.f, 0.f, 0.f, 0.f};
      const int key = cb * 16 + (l & 15);
#pragma unroll
      for (int g = 0; g < 4; ++g) {
        const int ch = (g * 4 + (l >> 4)) ^ (key & 7);
        f16x8 kf = *(const f16x8*)&lK[key * 128 + ch * 8];
        s = __builtin_amdgcn_mfma_f32_16x16x32_f16(qf[g], kf, s, 0, 0, 0);
      }
#pragma unroll
      for (int j = 0; j < 4; j++) lsum[j] += __expf(s[j]);
    }
  }
#pragma unroll
  for (int j = 0; j < 4; j++) {
    float v = lsum[j];
    v += __shfl_xor(v, 1);
    v += __shfl_xor(v, 2);
    v += __shfl_xor(v, 4);
    v += __shfl_xor(v, 8);
    lsum[j] = 1.0f / v;
  }

  // ---- pass 2: recompute S, write normalized P, accumulate PV
  f32x4 oacc[8] = {};
  float* Prow = Pout + ((size_t)bh * SEQ + q0) * SEQ;
  for (int kb = 0; kb < 32; ++kb) {
    __syncthreads();
    {
      const int t = l >> 4, sl = l & 15;
#pragma unroll
      for (int c = 0; c < 4; c++) {
        const int row = w * 16 + c * 4 + t;
        const int ch = sl ^ (row & 7);
        gload16(Kb + (size_t)(kb * 64 + row) * HD + ch * 8, lK + w * 2048 + c * 512);
      }
      const int t8 = l >> 3, sl8 = l & 7;
#pragma unroll
      for (int c = 0; c < 4; c++) {
        const int row = w * 32 + c * 8 + t8;
        const int ch = sl8 ^ (row & 7);
        gload16(Vb + (size_t)row * SEQ + kb * 64 + ch * 8, lV + w * 2048 + c * 512);
      }
    }
    __syncthreads();
#pragma unroll
    for (int cb = 0; cb < 4; ++cb) {
      f32x4 s = {0.f, 0.f, 0.f, 0.f};
      const int key = cb * 16 + (l & 15);
#pragma unroll
      for (int g = 0; g < 4; ++g) {
        const int ch = (g * 4 + (l >> 4)) ^ (key & 7);
        f16x8 kf = *(const f16x8*)&lK[key * 128 + ch * 8];
        s = __builtin_amdgcn_mfma_f32_16x16x32_f16(qf[g], kf, s, 0, 0, 0);
      }
#pragma unroll
      for (int j = 0; j < 4; j++) {
        const float p = __expf(s[j]) * lsum[j];
        const int lrow = w * 16 + (l >> 4) * 4 + j;
        Prow[(size_t)lrow * SEQ + kb * 64 + key] = p;
        const int ch = (key >> 3) ^ (lrow & 7);
        lP[lrow * 64 + ch * 8 + (key & 7)] = (f16)p;
      }
    }
    __syncthreads();
    f16x8 pf[2];
    {
      const int row = w * 16 + (l & 15);
#pragma unroll
      for (int ks = 0; ks < 2; ++ks) {
        const int ch = (ks * 4 + (l >> 4)) ^ (row & 7);
        pf[ks] = *(const f16x8*)&lP[row * 64 + ch * 8];
      }
    }
#pragma unroll
    for (int cb = 0; cb < 8; ++cb) {
      const int d = cb * 16 + (l & 15);
#pragma unroll
      for (int ks = 0; ks < 2; ++ks) {
        const int ch = (ks * 4 + (l >> 4)) ^ (d & 7);
        f16x8 vf = *(const f16x8*)&lV[d * 64 + ch * 8];
        oacc[cb] = __builtin_amdgcn_mfma_f32_16x16x32_f16(pf[ks], vf, oacc[cb], 0, 0, 0);
      }
    }
  }
  // O epilogue: [b,h,q,d] -> merged [n][2048] f16 for the final GEMM
  const int b = bh >> 4, h = bh & 15;
#pragma unroll
  for (int cb = 0; cb < 8; ++cb) {
    const int d = cb * 16 + (l & 15);
#pragma unroll
    for (int j = 0; j < 4; j++) {
      const int lrow = w * 16 + (l >> 4) * 4 + j;
      Oout[((size_t)(b * SEQ + q0 + lrow)) * DM + h * HD + d] = (f16)oacc[cb][j];
    }
  }
}

extern "C" void kernel_launch(void* const* d_in, const int* in_sizes, int n_in,
                              void* d_out, int out_size, void* d_ws, size_t ws_size,
                              hipStream_t stream) {
  const float* hs = (const float*)d_in[0];
  const float* Wq = (const float*)d_in[1];
  const float* bq = (const float*)d_in[2];
  const float* Wk = (const float*)d_in[3];
  const float* Wv = (const float*)d_in[4];
  const float* bv = (const float*)d_in[5];
  const float* Wo = (const float*)d_in[6];
  const float* bo = (const float*)d_in[7];
  float* out = (float*)d_out;
  float* Pout = out + (size_t)NT * DM;  // attn_weights region (134M f32)

  // d_ws: 4 x 16 MiB f16 buffers = 64 MiB
  f16* q16 = (f16*)d_ws;
  f16* k16 = q16 + (size_t)NT * DM;
  f16* vt16 = k16 + (size_t)NT * DM;
  f16* ao16 = vt16 + (size_t)NT * DM;
  // hs16 + Wq/Wk/Wv f16 scratch lives inside the P output region (fully
  // overwritten by attn later); Wo16 reuses q16 slot after attn is done.
  f16* hs16 = (f16*)Pout;
  f16* wq16 = hs16 + (size_t)NT * DM;
  f16* wk16 = wq16 + (size_t)DM * DM;
  f16* wv16 = wk16 + (size_t)DM * DM;
  f16* wo16 = q16;

  cvt_f32_f16<<<2048, 256, 0, stream>>>(hs, hs16, NT * DM / 4);
  cvt_f32_f16<<<1024, 256, 0, stream>>>(Wq, wq16, DM * DM / 4);
  cvt_f32_f16<<<1024, 256, 0, stream>>>(Wk, wk16, DM * DM / 4);
  cvt_f32_f16<<<1024, 256, 0, stream>>>(Wv, wv16, DM * DM / 4);

  dim3 gg(DM / 128, NT / 128);
  gemm_bt<1><<<gg, 256, 0, stream>>>(hs16, wq16, bq, nullptr, q16, SCALE);
  gemm_bt<1><<<gg, 256, 0, stream>>>(hs16, wk16, nullptr, nullptr, k16, 1.0f);
  gemm_bt<2><<<gg, 256, 0, stream>>>(hs16, wv16, bv, nullptr, vt16, 1.0f);

  attn<<<dim3(SEQ / 64, NBH), 256, 0, stream>>>(q16, k16, vt16, Pout, ao16);

  cvt_f32_f16<<<1024, 256, 0, stream>>>(Wo, wo16, DM * DM / 4);
  gemm_bt<0><<<gg, 256, 0, stream>>>(ao16, wo16, bo, out, nullptr, 1.0f);
}

// Round 3
// 470.027 us; speedup vs baseline: 1.0653x; 1.0653x over previous
//
#include <hip/hip_runtime.h>

typedef _Float16 f16;
typedef _Float16 f16x4 __attribute__((ext_vector_type(4)));
typedef _Float16 f16x8 __attribute__((ext_vector_type(8)));
typedef float f32x4 __attribute__((ext_vector_type(4)));

#define DM 2048
#define NT 4096
#define SEQ 2048
#define HD 128
#define NBH 32
// 1/sqrt(128) * log2(e): scores come out in log2 domain -> exp2 is one v_exp_f32
#define QSCALE (0.08838834764831845f * 1.4426950408889634f)

__device__ __forceinline__ void gload16(const f16* g, f16* l) {
  __builtin_amdgcn_global_load_lds(
      (const __attribute__((address_space(1))) void*)g,
      (__attribute__((address_space(3))) void*)l, 16, 0, 0);
}

__global__ __launch_bounds__(256) void cvt_f32_f16(const float* __restrict__ src,
                                                   f16* __restrict__ dst, int n4) {
  int i = blockIdx.x * 256 + threadIdx.x;
  int st = gridDim.x * 256;
  for (; i < n4; i += st) {
    float4 v = ((const float4*)src)[i];
    f16x4 h = {(f16)v.x, (f16)v.y, (f16)v.z, (f16)v.w};
    ((f16x4*)dst)[i] = h;
  }
}

// C = A(4096xK) * B^T, B row-major [N][K]=[2048][2048]. 128x128 tile, BK=32.
// MODE 0: f32 out [n][2048] + bias (final O projection)
// MODE 1: f16 out in [b,h,s,d] head layout, (optional bias), * scale   (Q, K)
// MODE 2: f16 out in [b,h,d,s] transposed head layout + bias           (V)
template <int MODE>
__global__ __launch_bounds__(256, 2) void gemm_bt(const f16* __restrict__ A,
                                                  const f16* __restrict__ B,
                                                  const float* __restrict__ bias,
                                                  float* __restrict__ outF,
                                                  f16* __restrict__ outH, float scale) {
  __shared__ __align__(16) f16 lA[128 * 32];
  __shared__ __align__(16) f16 lB[128 * 32];
  const int tid = threadIdx.x;
  const int w = tid >> 6, l = tid & 63;
  const int wr = w >> 1, wc = w & 1;
  const int row0 = blockIdx.y * 128, col0 = blockIdx.x * 128;

  f32x4 acc[4][4] = {};

  const int srow = w * 32 + (l >> 2);  // staging row (c=0); +16 for c=1
  const int sk = (l & 3) * 8;
  const f16* gA = A + (size_t)(row0 + srow) * DM + sk;
  const f16* gB = B + (size_t)(col0 + srow) * DM + sk;
  f16* sA = lA + w * 1024;
  f16* sB = lB + w * 1024;

  for (int k0 = 0; k0 < DM; k0 += 32) {
    __syncthreads();
    gload16(gA + k0, sA);
    gload16(gA + k0 + 16 * DM, sA + 512);
    gload16(gB + k0, sB);
    gload16(gB + k0 + 16 * DM, sB + 512);
    __syncthreads();
    f16x8 af[4], bf[4];
#pragma unroll
    for (int i = 0; i < 4; i++)
      af[i] = *(const f16x8*)&lA[(wr * 64 + i * 16 + (l & 15)) * 32 + (l >> 4) * 8];
#pragma unroll
    for (int i = 0; i < 4; i++)
      bf[i] = *(const f16x8*)&lB[(wc * 64 + i * 16 + (l & 15)) * 32 + (l >> 4) * 8];
#pragma unroll
    for (int mi = 0; mi < 4; mi++)
#pragma unroll
      for (int ni = 0; ni < 4; ni++)
        acc[mi][ni] = __builtin_amdgcn_mfma_f32_16x16x32_f16(af[mi], bf[ni], acc[mi][ni], 0, 0, 0);
  }

  const int r0 = row0 + wr * 64 + (l >> 4) * 4;
  const int c0 = col0 + wc * 64 + (l & 15);
#pragma unroll
  for (int mi = 0; mi < 4; mi++) {
#pragma unroll
    for (int ni = 0; ni < 4; ni++) {
      const int col = c0 + ni * 16;
      const float bi = bias ? bias[col] : 0.0f;
#pragma unroll
      for (int j = 0; j < 4; j++) {
        const int row = r0 + mi * 16 + j;
        const float v = acc[mi][ni][j] + bi;
        if constexpr (MODE == 0) {
          outF[(size_t)row * DM + col] = v;
        } else if constexpr (MODE == 1) {
          const int b = row >> 11, s = row & 2047, h = col >> 7, d = col & 127;
          outH[((size_t)(b * 16 + h) * SEQ + s) * HD + d] = (f16)(v * scale);
        } else {
          const int b = row >> 11, s = row & 2047, h = col >> 7, d = col & 127;
          outH[((size_t)(b * 16 + h) * HD + d) * SEQ + s] = (f16)v;
        }
      }
    }
  }
}

// Attention: one block = 64 q rows of one (b,h). Two passes over K/V in 64-key
// blocks, double-buffered staging (prefetch issued before compute, drained by
// the end-of-iteration barrier). Swapped QK^T (mfma(K,Q)) so each lane holds 4
// consecutive keys of one q-row -> vectorized f32x4 P stores + f16x4 lP writes.
__global__ __launch_bounds__(256, 2) void attn(const f16* __restrict__ Q,
                                               const f16* __restrict__ Kt,
                                               const f16* __restrict__ Vt,
                                               float* __restrict__ Pout,
                                               f16* __restrict__ Oout) {
  __shared__ __align__(16) f16 smem[36864];  // 72 KiB -> 2 blocks/CU
  // layout: K0 @0, K1 @8192, V0 @16384, V1 @24576, lP @32768 (64x64, swizzled)
  f16* const lP = smem + 32768;

  const int tid = threadIdx.x, w = tid >> 6, l = tid & 63;
  const int t = l >> 4, sl = l & 15, t8 = l >> 3, sl8 = l & 7;
  const int bh = blockIdx.y, q0 = blockIdx.x * 64;
  const f16* Qg = Q + (size_t)bh * SEQ * HD;
  const f16* Kg = Kt + (size_t)bh * SEQ * HD;
  const f16* Vg = Vt + (size_t)bh * HD * SEQ;

  // ---- prologue: stage Q (into V0 slot) + K block 0 (into K0 slot), both async
#pragma unroll
  for (int c = 0; c < 4; c++) {
    const int row = w * 16 + c * 4 + t;
    const int ch = sl ^ (row & 7);
    gload16(Qg + (size_t)(q0 + row) * HD + ch * 8, smem + 16384 + w * 2048 + c * 512);
    gload16(Kg + (size_t)row * HD + ch * 8, smem + w * 2048 + c * 512);
  }
  __syncthreads();

  f16x8 qf[4];
  {
    const int row = w * 16 + sl;
#pragma unroll
    for (int g = 0; g < 4; g++) {
      const int ch = (g * 4 + t) ^ (row & 7);
      qf[g] = *(const f16x8*)&smem[16384 + row * 128 + ch * 8];
    }
  }

  float lsum = 0.0f;

  // ---- pass 1: row sums of exp2(S') (S' already in log2 domain via QSCALE)
  for (int kb = 0; kb < 32; ++kb) {
    f16* const kc = smem + (kb & 1) * 8192;
    if (kb < 31) {
      f16* const kn = smem + ((kb + 1) & 1) * 8192;
#pragma unroll
      for (int c = 0; c < 4; c++) {
        const int row = w * 16 + c * 4 + t;
        const int ch = sl ^ (row & 7);
        gload16(Kg + (size_t)((kb + 1) * 64 + row) * HD + ch * 8, kn + w * 2048 + c * 512);
      }
    }
#pragma unroll
    for (int cb = 0; cb < 4; ++cb) {
      f32x4 s = {0.f, 0.f, 0.f, 0.f};
      const int key = cb * 16 + sl;
#pragma unroll
      for (int g = 0; g < 4; ++g) {
        const int ch = (g * 4 + t) ^ (key & 7);
        f16x8 kf = *(const f16x8*)&kc[key * 128 + ch * 8];
        s = __builtin_amdgcn_mfma_f32_16x16x32_f16(kf, qf[g], s, 0, 0, 0);
      }
#pragma unroll
      for (int j = 0; j < 4; j++) lsum += __builtin_amdgcn_exp2f(s[j]);
    }
    __syncthreads();
  }
  lsum += __shfl_xor(lsum, 16);
  lsum += __shfl_xor(lsum, 32);
  const float inv = 1.0f / lsum;  // full row sum for qrow = w*16 + (l&15)

  // ---- pass 2 prologue: stage K0 + V0
  {
#pragma unroll
    for (int c = 0; c < 4; c++) {
      const int row = w * 16 + c * 4 + t;
      const int ch = sl ^ (row & 7);
      gload16(Kg + (size_t)row * HD + ch * 8, smem + w * 2048 + c * 512);
    }
#pragma unroll
    for (int c = 0; c < 4; c++) {
      const int row = w * 32 + c * 8 + t8;
      const int ch = sl8 ^ (row & 7);
      gload16(Vg + (size_t)row * SEQ + ch * 8, smem + 16384 + w * 2048 + c * 512);
    }
  }
  __syncthreads();

  f32x4 oacc[8] = {};
  const int qrow = w * 16 + sl;
  float* const Prow = Pout + ((size_t)bh * SEQ + q0 + qrow) * SEQ;

  // ---- pass 2: recompute S, write normalized P (f32x4), accumulate PV
  for (int kb = 0; kb < 32; ++kb) {
    f16* const kc = smem + (kb & 1) * 8192;
    f16* const vc = smem + 16384 + (kb & 1) * 8192;
    if (kb < 31) {
      f16* const kn = smem + ((kb + 1) & 1) * 8192;
      f16* const vn = smem + 16384 + ((kb + 1) & 1) * 8192;
#pragma unroll
      for (int c = 0; c < 4; c++) {
        const int row = w * 16 + c * 4 + t;
        const int ch = sl ^ (row & 7);
        gload16(Kg + (size_t)((kb + 1) * 64 + row) * HD + ch * 8, kn + w * 2048 + c * 512);
      }
#pragma unroll
      for (int c = 0; c < 4; c++) {
        const int row = w * 32 + c * 8 + t8;
        const int ch = sl8 ^ (row & 7);
        gload16(Vg + (size_t)row * SEQ + (kb + 1) * 64 + ch * 8, vn + w * 2048 + c * 512);
      }
    }
#pragma unroll
    for (int cb = 0; cb < 4; ++cb) {
      f32x4 s = {0.f, 0.f, 0.f, 0.f};
      const int key = cb * 16 + sl;
#pragma unroll
      for (int g = 0; g < 4; ++g) {
        const int ch = (g * 4 + t) ^ (key & 7);
        f16x8 kf = *(const f16x8*)&kc[key * 128 + ch * 8];
        s = __builtin_amdgcn_mfma_f32_16x16x32_f16(kf, qf[g], s, 0, 0, 0);
      }
      f32x4 p4;
      f16x4 ph;
#pragma unroll
      for (int j = 0; j < 4; j++) {
        const float p = __builtin_amdgcn_exp2f(s[j]) * inv;
        p4[j] = p;
        ph[j] = (f16)p;
      }
      // lane holds 4 consecutive keys (cb*16 + t*4 ..) of row qrow
      *(f32x4*)(Prow + kb * 64 + cb * 16 + t * 4) = p4;
      const int chs = (cb * 2 + (t >> 1)) ^ (qrow & 7);
      *(f16x4*)&lP[qrow * 64 + chs * 8 + (t & 1) * 4] = ph;
    }
    // lP rows are wave-private (rows w*16..w*16+15): no barrier needed,
    // compiler's lgkmcnt wait orders the ds_write -> ds_read.
    f16x8 pf[2];
#pragma unroll
    for (int ks = 0; ks < 2; ++ks) {
      const int ch = (ks * 4 + t) ^ (qrow & 7);
      pf[ks] = *(const f16x8*)&lP[qrow * 64 + ch * 8];
    }
    __builtin_amdgcn_s_setprio(1);
#pragma unroll
    for (int cb = 0; cb < 8; ++cb) {
      const int d = cb * 16 + sl;
#pragma unroll
      for (int ks = 0; ks < 2; ++ks) {
        const int ch = (ks * 4 + t) ^ (d & 7);
        f16x8 vf = *(const f16x8*)&vc[d * 64 + ch * 8];
        oacc[cb] = __builtin_amdgcn_mfma_f32_16x16x32_f16(pf[ks], vf, oacc[cb], 0, 0, 0);
      }
    }
    __builtin_amdgcn_s_setprio(0);
    __syncthreads();
  }

  // O epilogue: [b,h,q,d] -> merged [n][2048] f16 for the final GEMM
  const int b = bh >> 4, h = bh & 15;
#pragma unroll
  for (int cb = 0; cb < 8; ++cb) {
    const int d = cb * 16 + sl;
#pragma unroll
    for (int j = 0; j < 4; j++) {
      const int lrow = w * 16 + t * 4 + j;
      Oout[((size_t)(b * SEQ + q0 + lrow)) * DM + h * HD + d] = (f16)oacc[cb][j];
    }
  }
}

extern "C" void kernel_launch(void* const* d_in, const int* in_sizes, int n_in,
                              void* d_out, int out_size, void* d_ws, size_t ws_size,
                              hipStream_t stream) {
  const float* hs = (const float*)d_in[0];
  const float* Wq = (const float*)d_in[1];
  const float* bq = (const float*)d_in[2];
  const float* Wk = (const float*)d_in[3];
  const float* Wv = (const float*)d_in[4];
  const float* bv = (const float*)d_in[5];
  const float* Wo = (const float*)d_in[6];
  const float* bo = (const float*)d_in[7];
  float* out = (float*)d_out;
  float* Pout = out + (size_t)NT * DM;  // attn_weights region (134M f32)

  // d_ws: 4 x 16 MiB f16 buffers = 64 MiB
  f16* q16 = (f16*)d_ws;
  f16* k16 = q16 + (size_t)NT * DM;
  f16* vt16 = k16 + (size_t)NT * DM;
  f16* ao16 = vt16 + (size_t)NT * DM;
  // hs16 + Wq/Wk/Wv f16 scratch lives inside the P output region (fully
  // overwritten by attn later); Wo16 reuses q16 slot after attn is done.
  f16* hs16 = (f16*)Pout;
  f16* wq16 = hs16 + (size_t)NT * DM;
  f16* wk16 = wq16 + (size_t)DM * DM;
  f16* wv16 = wk16 + (size_t)DM * DM;
  f16* wo16 = q16;

  cvt_f32_f16<<<2048, 256, 0, stream>>>(hs, hs16, NT * DM / 4);
  cvt_f32_f16<<<1024, 256, 0, stream>>>(Wq, wq16, DM * DM / 4);
  cvt_f32_f16<<<1024, 256, 0, stream>>>(Wk, wk16, DM * DM / 4);
  cvt_f32_f16<<<1024, 256, 0, stream>>>(Wv, wv16, DM * DM / 4);

  dim3 gg(DM / 128, NT / 128);
  gemm_bt<1><<<gg, 256, 0, stream>>>(hs16, wq16, bq, nullptr, q16, QSCALE);
  gemm_bt<1><<<gg, 256, 0, stream>>>(hs16, wk16, nullptr, nullptr, k16, 1.0f);
  gemm_bt<2><<<gg, 256, 0, stream>>>(hs16, wv16, bv, nullptr, vt16, 1.0f);

  attn<<<dim3(SEQ / 64, NBH), 256, 0, stream>>>(q16, k16, vt16, Pout, ao16);

  cvt_f32_f16<<<1024, 256, 0, stream>>>(Wo, wo16, DM * DM / 4);
  gemm_bt<0><<<gg, 256, 0, stream>>>(ao16, wo16, bo, out, nullptr, 1.0f);
}